// Round 3
// baseline (404.382 us; speedup 1.0000x reference)
//
#include <hip/hip_runtime.h>

#define NATT 4096

// ---------------------------------------------------------------------------
// Kernel 1: self-attention over 64x64 (N=4096, C=2) + gamma*out + y  -> y1 (ws)
// 256 blocks x 256 threads. Per block: one batch, 64 query positions.
// LDS holds (k0,k1,v0,v1) per j as float4, segment-rotated to avoid conflicts.
// Softmax without max-subtraction: |e| <= ~30 so exp() is safe in fp32.
// ---------------------------------------------------------------------------
__global__ __launch_bounds__(256) void attn_y1_kernel(
    const float* __restrict__ y,
    const float* __restrict__ wq, const float* __restrict__ bq,
    const float* __restrict__ wk, const float* __restrict__ bk,
    const float* __restrict__ wv, const float* __restrict__ bv,
    const float* __restrict__ gammaP,
    float* __restrict__ y1out)
{
    __shared__ float kv[16 * 1024];   // 64 KB
    const int tid = threadIdx.x;
    const int blk = blockIdx.x;       // 256
    const int b   = blk >> 6;         // 0..3
    const int i0  = (blk & 63) << 6;  // 64 i per block
    const float* yb = y + (size_t)b * 2 * NATT;

    const float wk00 = wk[0], wk01 = wk[1], wk10 = wk[2], wk11 = wk[3];
    const float wv00 = wv[0], wv01 = wv[1], wv10 = wv[2], wv11 = wv[3];
    const float bk0 = bk[0], bk1 = bk[1], bv0 = bv[0], bv1 = bv[1];

    // stage k,v for all 4096 positions: thread handles j = tid + 256*t
#pragma unroll
    for (int t = 0; t < 16; ++t) {
        int j = tid + (t << 8);
        float ya  = yb[j];
        float ybv = yb[NATT + j];
        float k0 = wk00 * ya + wk01 * ybv + bk0;
        float k1 = wk10 * ya + wk11 * ybv + bk1;
        float v0 = wv00 * ya + wv01 * ybv + bv0;
        float v1 = wv10 * ya + wv11 * ybv + bv1;
        // jseg = t, jj = tid; rotate jj by jseg so bank groups differ
        int addr = (t << 10) + (((tid + t) & 255) << 2);
        *(float4*)&kv[addr] = make_float4(k0, k1, v0, v1);
    }
    __syncthreads();

    const int jseg = tid & 15;   // 16-way split of j
    const int ii   = tid >> 4;   // 16 i-groups

    const float wq00 = wq[0], wq01 = wq[1], wq10 = wq[2], wq11 = wq[3];
    const float bq0 = bq[0], bq1 = bq[1];

    float q0[4], q1[4];
#pragma unroll
    for (int m = 0; m < 4; ++m) {
        int i = i0 + ii + (m << 4);
        float ya = yb[i], ybv = yb[NATT + i];
        q0[m] = wq00 * ya + wq01 * ybv + bq0;
        q1[m] = wq10 * ya + wq11 * ybv + bq1;
    }

    float s[4]  = {0.f, 0.f, 0.f, 0.f};
    float a0[4] = {0.f, 0.f, 0.f, 0.f};
    float a1[4] = {0.f, 0.f, 0.f, 0.f};
    const int base = jseg << 10;
#pragma unroll 4
    for (int jj = 0; jj < 256; ++jj) {
        float4 kvv = *(const float4*)&kv[base + (((jj + jseg) & 255) << 2)];
#pragma unroll
        for (int m = 0; m < 4; ++m) {
            float e = fmaf(q0[m], kvv.x, q1[m] * kvv.y);
            float p = __expf(e);
            s[m] += p;
            a0[m] = fmaf(p, kvv.z, a0[m]);
            a1[m] = fmaf(p, kvv.w, a1[m]);
        }
    }
    // merge the 16 j-segments (lane bits 0..3)
#pragma unroll
    for (int d = 1; d < 16; d <<= 1) {
#pragma unroll
        for (int m = 0; m < 4; ++m) {
            s[m]  += __shfl_xor(s[m],  d, 64);
            a0[m] += __shfl_xor(a0[m], d, 64);
            a1[m] += __shfl_xor(a1[m], d, 64);
        }
    }
    if (jseg == 0) {
        float g = gammaP[0];
#pragma unroll
        for (int m = 0; m < 4; ++m) {
            int i = i0 + ii + (m << 4);
            float o0 = a0[m] / s[m];
            float o1 = a1[m] / s[m];
            y1out[(size_t)b * 2 * NATT + i]        = g * o0 + yb[i];
            y1out[(size_t)b * 2 * NATT + NATT + i] = g * o1 + yb[NATT + i];
        }
    }
}

// ---------------------------------------------------------------------------
// Kernel 2: 3x3 conv partials. Channel dim split into G=32 groups of 32 ch.
// 512 blocks = 4 batch x 4 row-strips(32 rows) x 32 groups. 256 threads:
// col = tid&31 (owns 4 cols), rg = tid>>5 (owns 4 rows). Register rolling,
// neighbors via __shfl; halo rows dedup in L1. Partials -> ws (16 MB).
// ---------------------------------------------------------------------------
__global__ __launch_bounds__(256) void conv_part_kernel(
    const float* __restrict__ x, const float* __restrict__ cw,
    float* __restrict__ part)
{
    const int bid = blockIdx.x;      // 512
    const int g = bid & 31;
    const int s = (bid >> 5) & 3;
    const int b = bid >> 7;
    const int tid = threadIdx.x;
    const int col = tid & 31;
    const int rg  = tid >> 5;
    const int rowbase = (s << 5) + (rg << 2);
    const int lane = tid & 63;

    const float* xp  = x + (((size_t)(b * 1024 + g * 32)) << 14) + (col << 2);
    const float* w0p = cw + (size_t)g * 32 * 9;          // oc=0 weights
    const float* w1p = w0p + 9216;                       // oc=1 (1024*9)

    float4 acc[4][2];
#pragma unroll
    for (int i = 0; i < 4; ++i)
#pragma unroll
        for (int oc = 0; oc < 2; ++oc)
            acc[i][oc] = make_float4(0.f, 0.f, 0.f, 0.f);

    float4 cur[6], nxt[6];
    auto loadrows = [&](int c, float4* dst) {
        const float* xc = xp + ((size_t)c << 14);
#pragma unroll
        for (int k = 0; k < 6; ++k) {
            int gr  = rowbase - 1 + k;
            int grc = gr < 0 ? 0 : (gr > 127 ? 127 : gr);
            float4 v = *(const float4*)(xc + (grc << 7));
            if (gr < 0 || gr > 127) v = make_float4(0.f, 0.f, 0.f, 0.f);
            dst[k] = v;
        }
    };

    loadrows(0, cur);
#pragma unroll 1
    for (int ci = 0; ci < 32; ++ci) {
        if (ci < 31) loadrows(ci + 1, nxt);   // prefetch next channel
        const float* wa = w0p + ci * 9;
        const float* wb = w1p + ci * 9;
        float W[2][9];
#pragma unroll
        for (int t = 0; t < 9; ++t) { W[0][t] = wa[t]; W[1][t] = wb[t]; }

        float lf[6], rf[6];
#pragma unroll
        for (int k = 0; k < 6; ++k) {
            float lv = __shfl(cur[k].w, (lane - 1) & 63, 64);
            float rv = __shfl(cur[k].x, (lane + 1) & 63, 64);
            lf[k] = (col == 0)  ? 0.f : lv;   // image-left zero pad
            rf[k] = (col == 31) ? 0.f : rv;   // image-right zero pad
        }
#pragma unroll
        for (int i = 0; i < 4; ++i) {
#pragma unroll
            for (int dr = 0; dr < 3; ++dr) {
                const int k = i + dr;
                const float f0 = lf[k],  f1 = cur[k].x, f2 = cur[k].y,
                            f3 = cur[k].z, f4 = cur[k].w, f5 = rf[k];
#pragma unroll
                for (int oc = 0; oc < 2; ++oc) {
                    const float w0 = W[oc][dr * 3 + 0];
                    const float w1 = W[oc][dr * 3 + 1];
                    const float w2 = W[oc][dr * 3 + 2];
                    acc[i][oc].x = fmaf(w0, f0, fmaf(w1, f1, fmaf(w2, f2, acc[i][oc].x)));
                    acc[i][oc].y = fmaf(w0, f1, fmaf(w1, f2, fmaf(w2, f3, acc[i][oc].y)));
                    acc[i][oc].z = fmaf(w0, f2, fmaf(w1, f3, fmaf(w2, f4, acc[i][oc].z)));
                    acc[i][oc].w = fmaf(w0, f3, fmaf(w1, f4, fmaf(w2, f5, acc[i][oc].w)));
                }
            }
        }
        if (ci < 31) {
#pragma unroll
            for (int k = 0; k < 6; ++k) cur[k] = nxt[k];
        }
    }

    // partial layout: [g][b][oc][h][w]  (slab == output layout)
    float* pb = part + (((size_t)(g * 4 + b) * 2) << 14) + (col << 2);
#pragma unroll
    for (int i = 0; i < 4; ++i) {
        int orow = rowbase + i;
        *(float4*)(pb + (orow << 7))             = acc[i][0];
        *(float4*)(pb + (1 << 14) + (orow << 7)) = acc[i][1];
    }
}

// ---------------------------------------------------------------------------
// Kernel 3: reduce 32 partials + bias + BN + ReLU, bilinear-upsample y and y1
// (align_corners=True, 64->128), final combine -> out.
// ---------------------------------------------------------------------------
__global__ __launch_bounds__(256) void combine_kernel(
    const float* __restrict__ part,
    const float* __restrict__ y,
    const float* __restrict__ y1w,
    const float* __restrict__ convb,
    const float* __restrict__ bns, const float* __restrict__ bnb,
    const float* __restrict__ bnm, const float* __restrict__ bnv,
    float* __restrict__ out)
{
    const int idx = blockIdx.x * 256 + threadIdx.x;   // 131072
    const int w  = idx & 127;
    const int h  = (idx >> 7) & 127;
    const int oc = (idx >> 14) & 1;
    const int b  = idx >> 15;

    float conv = 0.f;
#pragma unroll
    for (int g = 0; g < 32; ++g)
        conv += part[(size_t)g * 131072 + idx];
    conv += convb[oc];

    float inv = bns[oc] * rsqrtf(bnv[oc] + 1e-5f);
    float xc  = (conv - bnm[oc]) * inv + bnb[oc];
    xc = fmaxf(xc, 0.f);

    // align_corners=True: src = i * (64-1)/(128-1)
    float sy = (float)(h * 63) * (1.0f / 127.0f);
    int   y0i = (int)sy;
    float wy  = sy - (float)y0i;
    int   y1i = y0i < 63 ? y0i + 1 : 63;
    float sx = (float)(w * 63) * (1.0f / 127.0f);
    int   x0i = (int)sx;
    float wx  = sx - (float)x0i;
    int   x1i = x0i < 63 ? x0i + 1 : 63;

    const size_t cb = ((size_t)(b * 2 + oc)) << 12;   // 4096 per (b,c)
    const float* yc = y   + cb;
    const float* zc = y1w + cb;
    const int i00 = y0i * 64 + x0i, i01 = y0i * 64 + x1i;
    const int i10 = y1i * 64 + x0i, i11 = y1i * 64 + x1i;
    float yup = (1.f - wy) * ((1.f - wx) * yc[i00] + wx * yc[i01])
              +        wy  * ((1.f - wx) * yc[i10] + wx * yc[i11]);
    float zup = (1.f - wy) * ((1.f - wx) * zc[i00] + wx * zc[i01])
              +        wy  * ((1.f - wx) * zc[i10] + wx * zc[i11]);

    out[idx] = yup + xc * zup;
}

// ---------------------------------------------------------------------------
extern "C" void kernel_launch(void* const* d_in, const int* in_sizes, int n_in,
                              void* d_out, int out_size, void* d_ws, size_t ws_size,
                              hipStream_t stream)
{
    const float* x     = (const float*)d_in[0];
    const float* y     = (const float*)d_in[1];
    const float* wq    = (const float*)d_in[2];
    const float* bq    = (const float*)d_in[3];
    const float* wk    = (const float*)d_in[4];
    const float* bk    = (const float*)d_in[5];
    const float* wv    = (const float*)d_in[6];
    const float* bv    = (const float*)d_in[7];
    const float* gamma = (const float*)d_in[8];
    const float* cw    = (const float*)d_in[9];
    const float* cb    = (const float*)d_in[10];
    const float* bns   = (const float*)d_in[11];
    const float* bnb   = (const float*)d_in[12];
    const float* bnm   = (const float*)d_in[13];
    const float* bnv   = (const float*)d_in[14];

    float* out  = (float*)d_out;
    float* part = (float*)d_ws;                                  // 16 MB partials
    float* y1w  = (float*)((char*)d_ws + (size_t)32 * 131072 * 4); // 128 KB y1

    hipLaunchKernelGGL(conv_part_kernel, dim3(512), dim3(256), 0, stream, x, cw, part);
    hipLaunchKernelGGL(attn_y1_kernel,   dim3(256), dim3(256), 0, stream,
                       y, wq, bq, wk, bk, wv, bv, gamma, y1w);
    hipLaunchKernelGGL(combine_kernel,   dim3(512), dim3(256), 0, stream,
                       part, y, y1w, cb, bns, bnb, bnm, bnv, out);
}

// Round 4
// 393.840 us; speedup vs baseline: 1.0268x; 1.0268x over previous
//
#include <hip/hip_runtime.h>

#define NATT 4096
#define NCONV 256   // blocks 0..255 = conv partials; 256..511 = attention

// ---------------------------------------------------------------------------
// Fused kernel: heterogeneous grid.
//  - conv half: 3x3 conv partials, 16 groups x 64 channels. Block = (b, strip,
//    group); 256 threads: col=tid&31 (4 cols via float4), rg=tid>>5 (4 rows).
//    Register-rolling channel loop, halo via __shfl, partials -> ws.
//  - attn half: self-attention over N=4096, C=2, one batch x 64 queries per
//    block. KV staged in 64 KB LDS (segment-rotated float4). Max-free softmax
//    (|e| small, fp32 exp safe). y1 = gamma*attn_out + y -> ws.
// 64 KB static LDS caps occupancy at 2 blocks/CU -> all 512 blocks co-resident,
// pairing one BW-bound conv block with one VALU-bound attn block per CU.
// ---------------------------------------------------------------------------
__global__ __launch_bounds__(256) void fused_conv_attn_kernel(
    const float* __restrict__ x, const float* __restrict__ cw,
    const float* __restrict__ y,
    const float* __restrict__ wq, const float* __restrict__ bq,
    const float* __restrict__ wk, const float* __restrict__ bk,
    const float* __restrict__ wv, const float* __restrict__ bv,
    const float* __restrict__ gammaP,
    float* __restrict__ part, float* __restrict__ y1out)
{
    __shared__ float kv[16 * 1024];   // 64 KB, used by attn blocks only
    const int bid = blockIdx.x;
    const int tid = threadIdx.x;

    if (bid < NCONV) {
        // ------------------- conv partials -------------------
        const int g = bid & 15;          // channel group (64 ch)
        const int s = (bid >> 4) & 3;    // 32-row strip
        const int b = bid >> 6;          // batch
        const int col = tid & 31;
        const int rg  = tid >> 5;
        const int rowbase = (s << 5) + (rg << 2);
        const int lane = tid & 63;

        const float* xp  = x + (((size_t)(b * 1024 + g * 64)) << 14) + (col << 2);
        const float* w0p = cw + (size_t)g * 64 * 9;   // oc=0 weights for this group
        const float* w1p = w0p + 9216;                // oc=1 (1024*9)

        float4 acc[4][2];
#pragma unroll
        for (int i = 0; i < 4; ++i)
#pragma unroll
            for (int oc = 0; oc < 2; ++oc)
                acc[i][oc] = make_float4(0.f, 0.f, 0.f, 0.f);

        float4 cur[6], nxt[6];
        auto loadrows = [&](int c, float4* dst) {
            const float* xc = xp + ((size_t)c << 14);
#pragma unroll
            for (int k = 0; k < 6; ++k) {
                int gr  = rowbase - 1 + k;
                int grc = gr < 0 ? 0 : (gr > 127 ? 127 : gr);
                float4 v = *(const float4*)(xc + (grc << 7));
                if (gr < 0 || gr > 127) v = make_float4(0.f, 0.f, 0.f, 0.f);
                dst[k] = v;
            }
        };

        loadrows(0, cur);
#pragma unroll 1
        for (int ci = 0; ci < 64; ++ci) {
            if (ci < 63) loadrows(ci + 1, nxt);   // prefetch next channel
            const float* wa = w0p + ci * 9;
            const float* wb = w1p + ci * 9;
            float W[2][9];
#pragma unroll
            for (int t = 0; t < 9; ++t) { W[0][t] = wa[t]; W[1][t] = wb[t]; }

            float lf[6], rf[6];
#pragma unroll
            for (int k = 0; k < 6; ++k) {
                float lv = __shfl(cur[k].w, (lane - 1) & 63, 64);
                float rv = __shfl(cur[k].x, (lane + 1) & 63, 64);
                lf[k] = (col == 0)  ? 0.f : lv;   // image-left zero pad
                rf[k] = (col == 31) ? 0.f : rv;   // image-right zero pad
            }
#pragma unroll
            for (int i = 0; i < 4; ++i) {
#pragma unroll
                for (int dr = 0; dr < 3; ++dr) {
                    const int k = i + dr;
                    const float f0 = lf[k],  f1 = cur[k].x, f2 = cur[k].y,
                                f3 = cur[k].z, f4 = cur[k].w, f5 = rf[k];
#pragma unroll
                    for (int oc = 0; oc < 2; ++oc) {
                        const float w0 = W[oc][dr * 3 + 0];
                        const float w1 = W[oc][dr * 3 + 1];
                        const float w2 = W[oc][dr * 3 + 2];
                        acc[i][oc].x = fmaf(w0, f0, fmaf(w1, f1, fmaf(w2, f2, acc[i][oc].x)));
                        acc[i][oc].y = fmaf(w0, f1, fmaf(w1, f2, fmaf(w2, f3, acc[i][oc].y)));
                        acc[i][oc].z = fmaf(w0, f2, fmaf(w1, f3, fmaf(w2, f4, acc[i][oc].z)));
                        acc[i][oc].w = fmaf(w0, f3, fmaf(w1, f4, fmaf(w2, f5, acc[i][oc].w)));
                    }
                }
            }
            if (ci < 63) {
#pragma unroll
                for (int k = 0; k < 6; ++k) cur[k] = nxt[k];
            }
        }

        // partial layout: slab g (131072 floats) = [b][oc][h][w]
        float* pb = part + (size_t)g * 131072 + (((size_t)b * 2) << 14) + (col << 2);
#pragma unroll
        for (int i = 0; i < 4; ++i) {
            int orow = rowbase + i;
            *(float4*)(pb + (orow << 7))             = acc[i][0];
            *(float4*)(pb + (1 << 14) + (orow << 7)) = acc[i][1];
        }
    } else {
        // ------------------- attention + y1 -------------------
        const int blk = bid - NCONV;      // 0..255
        const int b   = blk >> 6;         // batch
        const int i0  = (blk & 63) << 6;  // 64 queries per block
        const float* yb = y + (size_t)b * 2 * NATT;

        const float wk00 = wk[0], wk01 = wk[1], wk10 = wk[2], wk11 = wk[3];
        const float wv00 = wv[0], wv01 = wv[1], wv10 = wv[2], wv11 = wv[3];
        const float bk0 = bk[0], bk1 = bk[1], bv0 = bv[0], bv1 = bv[1];

#pragma unroll
        for (int t = 0; t < 16; ++t) {
            int j = tid + (t << 8);
            float ya  = yb[j];
            float ybv = yb[NATT + j];
            float k0 = wk00 * ya + wk01 * ybv + bk0;
            float k1 = wk10 * ya + wk11 * ybv + bk1;
            float v0 = wv00 * ya + wv01 * ybv + bv0;
            float v1 = wv10 * ya + wv11 * ybv + bv1;
            int addr = (t << 10) + (((tid + t) & 255) << 2);   // segment-rotated
            *(float4*)&kv[addr] = make_float4(k0, k1, v0, v1);
        }
        __syncthreads();

        const int jseg = tid & 15;
        const int ii   = tid >> 4;

        const float wq00 = wq[0], wq01 = wq[1], wq10 = wq[2], wq11 = wq[3];
        const float bq0 = bq[0], bq1 = bq[1];

        float q0[4], q1[4];
#pragma unroll
        for (int m = 0; m < 4; ++m) {
            int i = i0 + ii + (m << 4);
            float ya = yb[i], ybv = yb[NATT + i];
            q0[m] = wq00 * ya + wq01 * ybv + bq0;
            q1[m] = wq10 * ya + wq11 * ybv + bq1;
        }

        float s[4]  = {0.f, 0.f, 0.f, 0.f};
        float a0[4] = {0.f, 0.f, 0.f, 0.f};
        float a1[4] = {0.f, 0.f, 0.f, 0.f};
        const int base = jseg << 10;
#pragma unroll 4
        for (int jj = 0; jj < 256; ++jj) {
            float4 kvv = *(const float4*)&kv[base + (((jj + jseg) & 255) << 2)];
#pragma unroll
            for (int m = 0; m < 4; ++m) {
                float e = fmaf(q0[m], kvv.x, q1[m] * kvv.y);
                float p = __expf(e);
                s[m] += p;
                a0[m] = fmaf(p, kvv.z, a0[m]);
                a1[m] = fmaf(p, kvv.w, a1[m]);
            }
        }
#pragma unroll
        for (int d = 1; d < 16; d <<= 1) {
#pragma unroll
            for (int m = 0; m < 4; ++m) {
                s[m]  += __shfl_xor(s[m],  d, 64);
                a0[m] += __shfl_xor(a0[m], d, 64);
                a1[m] += __shfl_xor(a1[m], d, 64);
            }
        }
        if (jseg == 0) {
            float g = gammaP[0];
#pragma unroll
            for (int m = 0; m < 4; ++m) {
                int i = i0 + ii + (m << 4);
                float o0 = a0[m] / s[m];
                float o1 = a1[m] / s[m];
                y1out[(size_t)b * 2 * NATT + i]        = g * o0 + yb[i];
                y1out[(size_t)b * 2 * NATT + NATT + i] = g * o1 + yb[NATT + i];
            }
        }
    }
}

// ---------------------------------------------------------------------------
// Combine: reduce 16 partial slabs (float4) + bias + BN + ReLU; bilinear
// upsample y and y1 (align_corners=True, 64->128); out = y_up + xc * y1_up.
// 128 blocks x 256 threads, 4 outputs/thread.
// ---------------------------------------------------------------------------
__global__ __launch_bounds__(256) void combine_kernel(
    const float* __restrict__ part,
    const float* __restrict__ y,
    const float* __restrict__ y1w,
    const float* __restrict__ convb,
    const float* __restrict__ bns, const float* __restrict__ bnb,
    const float* __restrict__ bnm, const float* __restrict__ bnv,
    float* __restrict__ out)
{
    const int t   = blockIdx.x * 256 + threadIdx.x;   // 32768
    const int idx = t << 2;
    const int w0c = idx & 127;
    const int h   = (idx >> 7) & 127;
    const int oc  = (idx >> 14) & 1;
    const int b   = idx >> 15;

    const float* pbase = part + (((size_t)(b * 2 + oc)) << 14) + (h << 7) + w0c;
    float cv[4] = {0.f, 0.f, 0.f, 0.f};
#pragma unroll
    for (int g = 0; g < 16; ++g) {
        float4 p = *(const float4*)(pbase + (size_t)g * 131072);
        cv[0] += p.x; cv[1] += p.y; cv[2] += p.z; cv[3] += p.w;
    }
    const float inv = bns[oc] * rsqrtf(bnv[oc] + 1e-5f);
    const float aff = (convb[oc] - bnm[oc]) * inv + bnb[oc];

    const float sy = (float)(h * 63) * (1.0f / 127.0f);
    const int   y0i = (int)sy;
    const float wy  = sy - (float)y0i;
    const int   y1i = y0i < 63 ? y0i + 1 : 63;

    const size_t cb = ((size_t)(b * 2 + oc)) << 12;   // 4096 per (b,c)
    const float* yc = y   + cb;
    const float* zc = y1w + cb;

    float res[4];
#pragma unroll
    for (int e = 0; e < 4; ++e) {
        float xc = fmaxf(fmaf(cv[e], inv, aff), 0.f);
        int w = w0c + e;
        float sx = (float)(w * 63) * (1.0f / 127.0f);
        int   x0i = (int)sx;
        float wx  = sx - (float)x0i;
        int   x1i = x0i < 63 ? x0i + 1 : 63;
        int i00 = y0i * 64 + x0i, i01 = y0i * 64 + x1i;
        int i10 = y1i * 64 + x0i, i11 = y1i * 64 + x1i;
        float yup = (1.f - wy) * ((1.f - wx) * yc[i00] + wx * yc[i01])
                  +        wy  * ((1.f - wx) * yc[i10] + wx * yc[i11]);
        float zup = (1.f - wy) * ((1.f - wx) * zc[i00] + wx * zc[i01])
                  +        wy  * ((1.f - wx) * zc[i10] + wx * zc[i11]);
        res[e] = yup + xc * zup;
    }
    *(float4*)&out[idx] = make_float4(res[0], res[1], res[2], res[3]);
}

// ---------------------------------------------------------------------------
extern "C" void kernel_launch(void* const* d_in, const int* in_sizes, int n_in,
                              void* d_out, int out_size, void* d_ws, size_t ws_size,
                              hipStream_t stream)
{
    const float* x     = (const float*)d_in[0];
    const float* y     = (const float*)d_in[1];
    const float* wq    = (const float*)d_in[2];
    const float* bq    = (const float*)d_in[3];
    const float* wk    = (const float*)d_in[4];
    const float* bk    = (const float*)d_in[5];
    const float* wv    = (const float*)d_in[6];
    const float* bv    = (const float*)d_in[7];
    const float* gamma = (const float*)d_in[8];
    const float* cw    = (const float*)d_in[9];
    const float* cb    = (const float*)d_in[10];
    const float* bns   = (const float*)d_in[11];
    const float* bnb   = (const float*)d_in[12];
    const float* bnm   = (const float*)d_in[13];
    const float* bnv   = (const float*)d_in[14];

    float* out  = (float*)d_out;
    float* part = (float*)d_ws;                                    // 8 MB partials (16 slabs)
    float* y1w  = (float*)((char*)d_ws + (size_t)16 * 131072 * 4); // +8 MB: y1 (128 KB)

    hipLaunchKernelGGL(fused_conv_attn_kernel, dim3(512), dim3(256), 0, stream,
                       x, cw, y, wq, bq, wk, bk, wv, bv, gamma, part, y1w);
    hipLaunchKernelGGL(combine_kernel, dim3(128), dim3(256), 0, stream,
                       part, y, y1w, cb, bns, bnb, bnm, bnv, out);
}